// Round 2
// baseline (1285.524 us; speedup 1.0000x reference)
//
#include <hip/hip_runtime.h>

// Problem constants
#define HH   1024
#define WW   2048
#define HWP  (HH * WW)          // 2,097,152 pixels
#define CC   34
#define NI   128
#define THING_LO 24
#define THING_HI 33
#define NTC  10                 // thing classes 24..33

// Native vector type for nontemporal stores (HIP float4 is a class -> rejected)
typedef float nfloat4 __attribute__((ext_vector_type(4)));

// Output layout (all float32, concatenated in return order)
#define OFF_CLASS  ((size_t)NI * HWP)
#define OFF_PROBS  (OFF_CLASS + NI)
#define OFF_SEGP   (OFF_PROBS + NI)
#define OFF_TOTAL  (OFF_SEGP + NI)
#define OFF_VALID  (OFF_TOTAL + NI)

// Workspace layout (bytes)
#define WS_COUNTS  0                         // int[NI*NTC] = 5120 B
#define WS_SEGSUM  (NI * NTC * 4)            // float[NI]
#define WS_CLS     (WS_SEGSUM + NI * 4)      // int[NI]
#define WS_TOT     (WS_CLS + NI * 4)         // int[NI]

__device__ __forceinline__ int thing_inst(int s, int im) {
    return (s >= THING_LO && s <= THING_HI) ? im : 0;
}

// K1: per-pixel pass. 4 pixels/thread. Writes all 128 mask planes (1 GiB,
// coalesced nontemporal float4) and accumulates (inst,cls) counts.
__global__ __launch_bounds__(256) void k1_mask_count(
    const int* __restrict__ seg, const int* __restrict__ imap,
    float* __restrict__ out_masks, int* __restrict__ counts)
{
    const int t = blockIdx.x * 256 + threadIdx.x;   // 0 .. HWP/4-1
    const int p = t * 4;
    const int4 sg = *reinterpret_cast<const int4*>(seg + p);
    const int4 im = *reinterpret_cast<const int4*>(imap + p);

    const int i0 = thing_inst(sg.x, im.x);
    const int i1 = thing_inst(sg.y, im.y);
    const int i2 = thing_inst(sg.z, im.z);
    const int i3 = thing_inst(sg.w, im.w);

    if (i0 > 0) atomicAdd(&counts[(i0 - 1) * NTC + (sg.x - THING_LO)], 1);
    if (i1 > 0) atomicAdd(&counts[(i1 - 1) * NTC + (sg.y - THING_LO)], 1);
    if (i2 > 0) atomicAdd(&counts[(i2 - 1) * NTC + (sg.z - THING_LO)], 1);
    if (i3 > 0) atomicAdd(&counts[(i3 - 1) * NTC + (sg.w - THING_LO)], 1);

    float* o = out_masks + p;
    #pragma unroll
    for (int i = 1; i <= NI; ++i) {
        nfloat4 v;
        v.x = (i0 == i) ? 1.0f : 0.0f;
        v.y = (i1 == i) ? 1.0f : 0.0f;
        v.z = (i2 == i) ? 1.0f : 0.0f;
        v.w = (i3 == i) ? 1.0f : 0.0f;
        __builtin_nontemporal_store(v, reinterpret_cast<nfloat4*>(o));
        o += HWP;
    }
}

// K2: one block of 128 threads. argmax over the 10 thing-class counts
// (strict > from low class == jnp.argmax first-max; all-zero row -> class 0,
// identical to argmax over the zero-padded 34-wide row). Writes the small
// outputs and zeroes seg_sum for K3.
__global__ __launch_bounds__(128) void k2_stats(
    const int* __restrict__ counts, const float* __restrict__ iprobs,
    float* __restrict__ out, int* __restrict__ cls_ws,
    int* __restrict__ tot_ws, float* __restrict__ seg_sum)
{
    const int i = threadIdx.x;      // 0..127 -> instance id i+1
    int bestv = 0, bestc = 0, tot = 0;
    #pragma unroll
    for (int j = 0; j < NTC; ++j) {
        const int c = counts[i * NTC + j];
        tot += c;
        if (c > bestv) { bestv = c; bestc = THING_LO + j; }
    }
    cls_ws[i] = bestc;
    tot_ws[i] = tot;
    seg_sum[i] = 0.0f;
    out[OFF_CLASS + i] = (float)bestc;
    out[OFF_PROBS + i] = iprobs[i];
    out[OFF_TOTAL + i] = (float)tot;
    out[OFF_VALID + i] = (tot > 0) ? 1.0f : 0.0f;
}

// K3: gather probs[cls[inst]][pix] for things-pixels; LDS-accumulate per
// block, flush 128 global float atomics per block.
__global__ __launch_bounds__(256) void k3_segsum(
    const int* __restrict__ seg, const int* __restrict__ imap,
    const float* __restrict__ probs, const int* __restrict__ cls_ws,
    float* __restrict__ seg_sum)
{
    __shared__ float lsum[NI];
    __shared__ int   scls[NI];
    if (threadIdx.x < NI) {
        lsum[threadIdx.x] = 0.0f;
        scls[threadIdx.x] = cls_ws[threadIdx.x];
    }
    __syncthreads();

    const int stride = gridDim.x * blockDim.x;
    for (int t = blockIdx.x * blockDim.x + threadIdx.x; t < HWP / 4; t += stride) {
        const int p = t * 4;
        const int4 sg = *reinterpret_cast<const int4*>(seg + p);
        const int4 im = *reinterpret_cast<const int4*>(imap + p);
        const int ii[4] = { thing_inst(sg.x, im.x), thing_inst(sg.y, im.y),
                            thing_inst(sg.z, im.z), thing_inst(sg.w, im.w) };
        #pragma unroll
        for (int k = 0; k < 4; ++k) {
            if (ii[k] > 0) {
                const int inst = ii[k] - 1;
                const size_t idx = (size_t)scls[inst] * HWP + (size_t)(p + k);
                atomicAdd(&lsum[inst], probs[idx]);
            }
        }
    }
    __syncthreads();
    if (threadIdx.x < NI) {
        const float v = lsum[threadIdx.x];
        if (v != 0.0f) atomicAdd(&seg_sum[threadIdx.x], v);
    }
}

// K4: final divide.
__global__ __launch_bounds__(128) void k4_segprob(
    const float* __restrict__ seg_sum, const int* __restrict__ tot_ws,
    float* __restrict__ out)
{
    const int i = threadIdx.x;
    const int t = tot_ws[i];
    out[OFF_SEGP + i] = seg_sum[i] / (float)(t > 0 ? t : 1);
}

extern "C" void kernel_launch(void* const* d_in, const int* in_sizes, int n_in,
                              void* d_out, int out_size, void* d_ws, size_t ws_size,
                              hipStream_t stream) {
    const int*   seg    = (const int*)d_in[0];     // (H,W) int32
    const int*   imap   = (const int*)d_in[1];     // (H,W) int32
    const float* probs  = (const float*)d_in[2];   // (C,H,W) f32
    const float* iprobs = (const float*)d_in[3];   // (NI,) f32
    float* out = (float*)d_out;

    char* ws = (char*)d_ws;
    int*   counts  = (int*)(ws + WS_COUNTS);
    float* seg_sum = (float*)(ws + WS_SEGSUM);
    int*   cls_ws  = (int*)(ws + WS_CLS);
    int*   tot_ws  = (int*)(ws + WS_TOT);

    // zero the count histogram (graph-capturable memset node)
    (void)hipMemsetAsync(counts, 0, NI * NTC * sizeof(int), stream);

    const int grid1 = (HWP / 4) / 256;   // 2048 blocks
    k1_mask_count<<<grid1, 256, 0, stream>>>(seg, imap, out, counts);
    k2_stats<<<1, 128, 0, stream>>>(counts, iprobs, out, cls_ws, tot_ws, seg_sum);
    k3_segsum<<<256, 256, 0, stream>>>(seg, imap, probs, cls_ws, seg_sum);
    k4_segprob<<<1, 128, 0, stream>>>(seg_sum, tot_ws, out);
}